// Round 10
// baseline (3192.600 us; speedup 1.0000x reference)
//
#include <hip/hip_runtime.h>
#include <math.h>

// LoRA-MLP, fp32 in/out. Fold rank-16 LoRA into weights (K=1), then two
// bf16 MFMA GEMMs: h = gelu(x@W1eff^T + b1); out = h@W2eff^T + b2.
// GEMM: one operand direct-from-global (L2-resident by schedule) with
// 1-iter register prefetch; the other reg-staged through LDS (r7-validated).
#define M_ROWS 12608   // 64*197
#define D_DIM  768
#define H_DIM  3072

typedef __bf16 bf16_t;
typedef __bf16 bf16x8 __attribute__((ext_vector_type(8)));
typedef float  f32x4  __attribute__((ext_vector_type(4)));

// Fast GELU via sigmoid form of tanh approximation (validated r6/r7).
__device__ __forceinline__ float gelu_fast(float v) {
  float v2 = v * v;
  float z = v * fmaf(0.044715f, v2, 1.0f);
  float e = __expf(-1.5957691216057308f * z);
  return v * __builtin_amdgcn_rcpf(1.0f + e);
}

// ---- merged prep: cast x (blocks 0..2363), fold1 (2364..3515), fold2 (..4667)
__device__ __forceinline__ void cast16(const float* __restrict__ in,
                                       bf16_t* __restrict__ out, int blk) {
  long i = ((long)blk * 256 + threadIdx.x) * 16;
  float4 v[4];
#pragma unroll
  for (int q = 0; q < 4; ++q) v[q] = *(const float4*)(in + i + q * 4);
  bf16_t ov[16];
#pragma unroll
  for (int q = 0; q < 4; ++q) {
    ov[q * 4 + 0] = (bf16_t)v[q].x; ov[q * 4 + 1] = (bf16_t)v[q].y;
    ov[q * 4 + 2] = (bf16_t)v[q].z; ov[q * 4 + 3] = (bf16_t)v[q].w;
  }
  *(bf16x8*)(out + i) = *(bf16x8*)ov;
  *(bf16x8*)(out + i + 8) = *(bf16x8*)(ov + 8);
}

__device__ __forceinline__ void fold8(const float* __restrict__ W,
                                      const float* __restrict__ A,
                                      const float* __restrict__ Bm,
                                      bf16_t* __restrict__ Weff,
                                      int IN, int blk) {
  const int nseg = IN >> 3;
  long idx = (long)blk * 256 + threadIdx.x;
  int o = (int)(idx / nseg);
  int s = (int)(idx - (long)o * nseg);
  const float* wp = W + (size_t)o * IN + s * 8;
  float4 w0 = *(const float4*)wp, w1 = *(const float4*)(wp + 4);
  float acc[8] = {w0.x, w0.y, w0.z, w0.w, w1.x, w1.y, w1.z, w1.w};
  float4 b4[4];
#pragma unroll
  for (int q = 0; q < 4; ++q) b4[q] = *(const float4*)(Bm + o * 16 + q * 4);
  const float* bb = (const float*)b4;
#pragma unroll
  for (int r = 0; r < 16; ++r) {
    float b = bb[r];
    const float* ap = A + (size_t)r * IN + s * 8;
    float4 a0 = *(const float4*)ap, a1 = *(const float4*)(ap + 4);
    acc[0] = fmaf(b, a0.x, acc[0]); acc[1] = fmaf(b, a0.y, acc[1]);
    acc[2] = fmaf(b, a0.z, acc[2]); acc[3] = fmaf(b, a0.w, acc[3]);
    acc[4] = fmaf(b, a1.x, acc[4]); acc[5] = fmaf(b, a1.y, acc[5]);
    acc[6] = fmaf(b, a1.z, acc[6]); acc[7] = fmaf(b, a1.w, acc[7]);
  }
  bf16_t ov[8];
#pragma unroll
  for (int i = 0; i < 8; ++i) ov[i] = (bf16_t)acc[i];
  *(bf16x8*)(Weff + (size_t)o * IN + s * 8) = *(bf16x8*)ov;
}

__global__ void prep_kernel(const float* __restrict__ x, bf16_t* __restrict__ xb,
                            const float* __restrict__ W1, const float* __restrict__ A1,
                            const float* __restrict__ B1, bf16_t* __restrict__ W1eff,
                            const float* __restrict__ W2, const float* __restrict__ A2,
                            const float* __restrict__ B2, bf16_t* __restrict__ W2eff) {
  int b = blockIdx.x;
  if (b < 2364) cast16(x, xb, b);
  else if (b < 3516) fold8(W1, A1, B1, W1eff, D_DIM, b - 2364);
  else fold8(W2, A2, B2, W2eff, H_DIM, b - 3516);
}

// Unified GEMM: C[m][n] = act(sum_k A[m][k]*B[n][k] + bias[n]).
// 128x128 tile, 4 waves 2x2 (64x64 wave, 4x4 acc of 16x16x32), BK=64.
// DIRECT operand (A if DIRECT_A else B): fragments loaded straight from
// global (L2-resident by schedule), REGISTER-PREFETCHED 1 iter ahead
// (ping-pong df0/df1, K-loop unrolled x2). LDS operand: reg-staged with
// 1-iter prefetch, XOR-swizzle slot kk^(r&7) (conflict-free), 2-barrier.
// SCHED 1 (GEMM1, DIRECT_A): per XCD rbands fast per col; xb band + W-col
//   L2-resident. SCHED 2 (GEMM2, DIRECT_B): 6 cols over two 4-XCD groups,
//   cols fast; W2eff col-group L2-resident, hbuf streamed via LDS.
template <bool GELU, typename OutT, int SCHED, bool DIRECT_A, int SMEM_BYTES>
__global__ __launch_bounds__(256, 3) void gemm_kernel(
    const bf16_t* __restrict__ Amat, const bf16_t* __restrict__ Bmat,
    const float* __restrict__ bias, OutT* __restrict__ Cmat,
    int Mrows, int Ncols, int Kd) {
  __shared__ char smem[SMEM_BYTES];
  bf16_t* lds = (bf16_t*)smem;   // LDS-operand tile [128][64] = 16KB
  float* sT = (float*)smem;      // GELU epilogue scratch [64][132] f32

  int rowb, colb;
  const int xcd = blockIdx.x & 7, t = blockIdx.x >> 3;
  if (SCHED == 1) {              // 24 cols x 13 rbands per XCD, rband-fast
    colb = t / 13;
    rowb = (t % 13) * 8 + xcd;
    if (rowb >= 99) return;
  } else {                       // 3 cols x 25 rbands per XCD, col-fast
    rowb = (t / 3) * 4 + (xcd & 3);
    if (rowb >= 99) return;
    colb = (xcd >> 2) * 3 + (t % 3);
  }
  const int row0 = rowb * 128, col0 = colb * 128;

  const int tid = threadIdx.x, lane = tid & 63, wave = tid >> 6;
  const int wm = wave & 1, wn = wave >> 1;
  const int rl = lane & 15, kc = lane >> 4;

  const bf16_t* Dmat = DIRECT_A ? Amat : Bmat;   // direct operand
  const bf16_t* Smat = DIRECT_A ? Bmat : Amat;   // LDS-staged operand
  const int dbase = DIRECT_A ? row0 : col0;
  const int sbase = DIRECT_A ? col0 : row0;
  const int wdir = DIRECT_A ? wm : wn;
  const int wlds = DIRECT_A ? wn : wm;

  // direct-fragment pointers: frag(di,ks,it) = 8 bf16 at row
  // dbase + wdir*64 + di*16 + rl, col it*64 + ks*32 + kc*8.
  const bf16_t* dP[4];
#pragma unroll
  for (int i = 0; i < 4; ++i) {
    int r = dbase + wdir * 64 + i * 16 + rl;
    if (DIRECT_A && r > Mrows - 1) r = Mrows - 1;   // M-edge clamp
    dP[i] = Dmat + (size_t)r * Kd + kc * 8;
  }

  // LDS staging: tile [128 rows][64 k] = 1024 16B-chunks, 4/thread.
  const bf16_t* gS[4];
  int offS[4];
#pragma unroll
  for (int q = 0; q < 4; ++q) {
    int c = tid + q * 256;
    int r = c >> 3, kkg = c & 7;
    int sr = sbase + r;
    if (!DIRECT_A && sr > Mrows - 1) sr = Mrows - 1;  // A-in-LDS M-edge clamp
    gS[q] = Smat + (size_t)sr * Kd + kkg * 8;
    offS[q] = r * 64 + (kkg ^ (r & 7)) * 8;
  }

  // LDS fragment offsets (ks=0; ks=1 -> element offset ^32)
  int soffs[4];
#pragma unroll
  for (int i = 0; i < 4; ++i) {
    int rr = wlds * 64 + i * 16 + rl;
    soffs[i] = rr * 64 + ((kc ^ (rr & 7)) * 8);
  }

  f32x4 acc[4][4] = {};
  f32x4 pS[4];
  bf16x8 df0[4][2], df1[4][2];
  const int iters = Kd / 64;   // 12 (G1) or 48 (G2): even

  // prologue: direct frags for it=0; LDS tile 0 -> regs -> LDS
#pragma unroll
  for (int i = 0; i < 4; ++i) {
    df0[i][0] = *(const bf16x8*)dP[i];
    df0[i][1] = *(const bf16x8*)(dP[i] + 32);
    dP[i] += 64;
  }
#pragma unroll
  for (int q = 0; q < 4; ++q) { pS[q] = *(const f32x4*)gS[q]; gS[q] += 64; }
#pragma unroll
  for (int q = 0; q < 4; ++q) *(f32x4*)(lds + offS[q]) = pS[q];
  __syncthreads();

  auto compute = [&](bf16x8 (&df)[4][2]) {
#pragma unroll
    for (int ks = 0; ks < 2; ++ks) {
      bf16x8 sf[4];
#pragma unroll
      for (int i = 0; i < 4; ++i)
        sf[i] = *(const bf16x8*)(lds + (soffs[i] ^ (ks * 32)));
#pragma unroll
      for (int di = 0; di < 4; ++di)
#pragma unroll
        for (int li = 0; li < 4; ++li) {
          if constexpr (DIRECT_A)
            acc[di][li] = __builtin_amdgcn_mfma_f32_16x16x32_bf16(
                df[di][ks], sf[li], acc[di][li], 0, 0, 0);
          else
            acc[li][di] = __builtin_amdgcn_mfma_f32_16x16x32_bf16(
                sf[li], df[di][ks], acc[li][di], 0, 0, 0);
        }
    }
  };
  auto prefetch = [&](bf16x8 (&dfn)[4][2]) {
#pragma unroll
    for (int q = 0; q < 4; ++q) { pS[q] = *(const f32x4*)gS[q]; gS[q] += 64; }
#pragma unroll
    for (int i = 0; i < 4; ++i) {
      dfn[i][0] = *(const bf16x8*)dP[i];
      dfn[i][1] = *(const bf16x8*)(dP[i] + 32);
      dP[i] += 64;
    }
  };
  auto stage = [&]() {   // barrier; write prefetched LDS tile; barrier
    __syncthreads();
#pragma unroll
    for (int q = 0; q < 4; ++q) *(f32x4*)(lds + offS[q]) = pS[q];
    __syncthreads();
  };

  for (int it = 0; it < iters; it += 2) {
    // even phase: compute it (df0), prefetch it+1 (df1)
    if (it + 1 < iters) {
      prefetch(df1);
      compute(df0);
      stage();
    } else {
      compute(df0);
      break;
    }
    // odd phase: compute it+1 (df1), prefetch it+2 (df0)
    if (it + 2 < iters) {
      prefetch(df0);
      compute(df1);
      stage();
    } else {
      compute(df1);
    }
  }

  // epilogue. C/D lane layout: col=lane&15, row=(lane>>4)*4+reg [m89-verified]
  const int crow = (lane >> 4) * 4, ccol = lane & 15;
  if constexpr (GELU) {
    __syncthreads();  // all waves done with LDS before sT reuse
#pragma unroll
    for (int p = 0; p < 2; ++p) {
#pragma unroll
      for (int s = 0; s < 2; ++s) {
        int mi = 2 * p + s;
#pragma unroll
        for (int ni = 0; ni < 4; ++ni)
#pragma unroll
          for (int r = 0; r < 4; ++r)
            sT[(wm * 32 + s * 16 + crow + r) * 132 + wn * 64 + ni * 16 + ccol] =
                acc[mi][ni][r];
      }
      __syncthreads();
      const int erow = tid >> 2, eseg = tid & 3;
      const int grow = row0 + (erow >> 5) * 64 + (2 * p + ((erow >> 4) & 1)) * 16 + (erow & 15);
      if (grow < Mrows) {
        const float* src = sT + erow * 132 + eseg * 32;
        const float* bsrc = bias + col0 + eseg * 32;
        bf16_t ov[32];
#pragma unroll
        for (int i = 0; i < 32; ++i)
          ov[i] = (bf16_t)gelu_fast(src[i] + bsrc[i]);
        bf16_t* dst = (bf16_t*)Cmat + (size_t)grow * Ncols + col0 + eseg * 32;
#pragma unroll
        for (int k = 0; k < 4; ++k)
          *(bf16x8*)(dst + k * 8) = *(bf16x8*)(ov + k * 8);
      }
      __syncthreads();
    }
  } else {
#pragma unroll
    for (int ni = 0; ni < 4; ++ni) {
      const int gc = col0 + wn * 64 + ni * 16 + ccol;
      const float bv = bias[gc];
#pragma unroll
      for (int mi = 0; mi < 4; ++mi) {
        const int gr = row0 + wm * 64 + mi * 16 + crow;
#pragma unroll
        for (int r = 0; r < 4; ++r) {
          const int row = gr + r;
          if (row < Mrows)
            Cmat[(size_t)row * Ncols + gc] = acc[mi][ni][r] + bv;
        }
      }
    }
  }
}

extern "C" void kernel_launch(void* const* d_in, const int* in_sizes, int n_in,
                              void* d_out, int out_size, void* d_ws, size_t ws_size,
                              hipStream_t stream) {
  const float* x  = (const float*)d_in[0];
  const float* W1 = (const float*)d_in[1];
  const float* b1 = (const float*)d_in[2];
  const float* A1 = (const float*)d_in[3];
  const float* B1 = (const float*)d_in[4];
  const float* W2 = (const float*)d_in[5];
  const float* b2 = (const float*)d_in[6];
  const float* A2 = (const float*)d_in[7];
  const float* B2 = (const float*)d_in[8];
  float* out = (float*)d_out;

  char* ws = (char*)d_ws;
  bf16_t* xb    = (bf16_t*)ws;                             // 19,365,888 B (pad)
  bf16_t* W1eff = (bf16_t*)(ws + 19366144);                //  4,718,592 B
  bf16_t* W2eff = (bf16_t*)(ws + 19366144 + 4718592);      //  4,718,592 B
  bf16_t* hbuf  = (bf16_t*)(ws + 19366144 + 2 * 4718592);  // 77,463,552 B

  // merged prep: cast (2364) + fold1 (1152) + fold2 (1152)
  prep_kernel<<<4668, 256, 0, stream>>>(x, xb, W1, A1, B1, W1eff,
                                        W2, A2, B2, W2eff);

  // GEMM1 (DIRECT_A): 99 rbands x 24 cols; per XCD 13 rbands rband-fast
  gemm_kernel<true, bf16_t, 1, true, 33792><<<2496, 256, 0, stream>>>(
      xb, W1eff, b1, hbuf, M_ROWS, H_DIM, D_DIM);
  // GEMM2 (DIRECT_B): 99 rbands x 6 cols; two 4-XCD groups x 3 cols col-fast
  gemm_kernel<false, float, 2, false, 16384><<<600, 256, 0, stream>>>(
      hbuf, W2eff, b2, out, M_ROWS, D_DIM, H_DIM);
}

// Round 11
// 297.089 us; speedup vs baseline: 10.7463x; 10.7463x over previous
//
#include <hip/hip_runtime.h>
#include <math.h>

// LoRA-MLP, fp32 in/out. Fold rank-16 LoRA into weights (K=1), then two
// bf16 MFMA GEMMs: h = gelu(x@W1eff^T + b1); out = h@W2eff^T + b2.
// GEMM = r7-validated structure: both operands reg-staged through LDS,
// 1-iter register prefetch, 2-barrier K-loop, BK=64, XOR-swizzled LDS.
#define M_ROWS 12608   // 64*197
#define D_DIM  768
#define H_DIM  3072

typedef __bf16 bf16_t;
typedef __bf16 bf16x8 __attribute__((ext_vector_type(8)));
typedef float  f32x4  __attribute__((ext_vector_type(4)));

// Fast GELU via sigmoid form of tanh approximation (validated r6/r7).
__device__ __forceinline__ float gelu_fast(float v) {
  float v2 = v * v;
  float z = v * fmaf(0.044715f, v2, 1.0f);
  float e = __expf(-1.5957691216057308f * z);
  return v * __builtin_amdgcn_rcpf(1.0f + e);
}

// ---- merged prep: cast x (blocks 0..2363), fold1 (2364..3515), fold2 (..4667)
__device__ __forceinline__ void cast16(const float* __restrict__ in,
                                       bf16_t* __restrict__ out, int blk) {
  long i = ((long)blk * 256 + threadIdx.x) * 16;
  float4 v[4];
#pragma unroll
  for (int q = 0; q < 4; ++q) v[q] = *(const float4*)(in + i + q * 4);
  bf16_t ov[16];
#pragma unroll
  for (int q = 0; q < 4; ++q) {
    ov[q * 4 + 0] = (bf16_t)v[q].x; ov[q * 4 + 1] = (bf16_t)v[q].y;
    ov[q * 4 + 2] = (bf16_t)v[q].z; ov[q * 4 + 3] = (bf16_t)v[q].w;
  }
  *(bf16x8*)(out + i) = *(bf16x8*)ov;
  *(bf16x8*)(out + i + 8) = *(bf16x8*)(ov + 8);
}

__device__ __forceinline__ void fold8(const float* __restrict__ W,
                                      const float* __restrict__ A,
                                      const float* __restrict__ Bm,
                                      bf16_t* __restrict__ Weff,
                                      int IN, int blk) {
  const int nseg = IN >> 3;
  long idx = (long)blk * 256 + threadIdx.x;
  int o = (int)(idx / nseg);
  int s = (int)(idx - (long)o * nseg);
  const float* wp = W + (size_t)o * IN + s * 8;
  float4 w0 = *(const float4*)wp, w1 = *(const float4*)(wp + 4);
  float acc[8] = {w0.x, w0.y, w0.z, w0.w, w1.x, w1.y, w1.z, w1.w};
  float4 b4[4];
#pragma unroll
  for (int q = 0; q < 4; ++q) b4[q] = *(const float4*)(Bm + o * 16 + q * 4);
  const float* bb = (const float*)b4;
#pragma unroll
  for (int r = 0; r < 16; ++r) {
    float b = bb[r];
    const float* ap = A + (size_t)r * IN + s * 8;
    float4 a0 = *(const float4*)ap, a1 = *(const float4*)(ap + 4);
    acc[0] = fmaf(b, a0.x, acc[0]); acc[1] = fmaf(b, a0.y, acc[1]);
    acc[2] = fmaf(b, a0.z, acc[2]); acc[3] = fmaf(b, a0.w, acc[3]);
    acc[4] = fmaf(b, a1.x, acc[4]); acc[5] = fmaf(b, a1.y, acc[5]);
    acc[6] = fmaf(b, a1.z, acc[6]); acc[7] = fmaf(b, a1.w, acc[7]);
  }
  bf16_t ov[8];
#pragma unroll
  for (int i = 0; i < 8; ++i) ov[i] = (bf16_t)acc[i];
  *(bf16x8*)(Weff + (size_t)o * IN + s * 8) = *(bf16x8*)ov;
}

__global__ void prep_kernel(const float* __restrict__ x, bf16_t* __restrict__ xb,
                            const float* __restrict__ W1, const float* __restrict__ A1,
                            const float* __restrict__ B1, bf16_t* __restrict__ W1eff,
                            const float* __restrict__ W2, const float* __restrict__ A2,
                            const float* __restrict__ B2, bf16_t* __restrict__ W2eff) {
  int b = blockIdx.x;
  if (b < 2364) cast16(x, xb, b);
  else if (b < 3516) fold8(W1, A1, B1, W1eff, D_DIM, b - 2364);
  else fold8(W2, A2, B2, W2eff, H_DIM, b - 3516);
}

// Unified GEMM (r7-validated): C[m][n] = act(sum_k A[m][k]*B[n][k] + bias[n]).
// 128x128 tile, 4 waves 2x2 (64x64 wave, 4x4 acc of 16x16x32), BK=64.
// REGISTER-STAGED pipeline, single LDS buffer: loads for tile it+1 are issued
// to VGPRs BEFORE computing tile it; the vmcnt wait lands before the ds_write
// AFTER compute -> one full compute phase of latency cover. NO lambdas for
// the pipeline arrays (r10 post-mortem: lambda-captured register arrays
// defeated SROA -> scratch spill -> 4.6 GB WRITE_SIZE).
// XOR-swizzle slot kk^(r&7): <=2-way bank aliasing (free, 0 conflicts).
// SCHED 1: per XCD, rbands fast per col (A-band L2-resident; r7 FETCH=62MB).
// SCHED 2: 6 cols over two 4-XCD groups, cols fast (W-cols L2-resident).
template <bool GELU, typename OutT, int SCHED, int SMEM_BYTES>
__global__ __launch_bounds__(256, 3) void gemm_kernel(
    const bf16_t* __restrict__ Amat, const bf16_t* __restrict__ Bmat,
    const float* __restrict__ bias, OutT* __restrict__ Cmat,
    int Mrows, int Ncols, int Kd) {
  __shared__ char smem[SMEM_BYTES];
  bf16_t* lds = (bf16_t*)smem;   // A: elements [0,8192), B: [8192,16384)
  float* sT = (float*)smem;      // GELU epilogue scratch [64][132] f32

  int rowb, colb;
  const int xcd = blockIdx.x & 7, t = blockIdx.x >> 3;
  if (SCHED == 1) {              // 24 cols x 13 rbands per XCD, rband-fast
    colb = t / 13;
    rowb = (t % 13) * 8 + xcd;
    if (rowb >= 99) return;
  } else {                       // 3 cols x 25 rbands per XCD, col-fast
    rowb = (t / 3) * 4 + (xcd & 3);
    if (rowb >= 99) return;
    colb = (xcd >> 2) * 3 + (t % 3);
  }
  const int row0 = rowb * 128, col0 = colb * 128;

  const int tid = threadIdx.x, lane = tid & 63, wave = tid >> 6;
  const int wm = wave & 1, wn = wave >> 1;

  // staging: A tile [128][64] = 1024 16B-chunks, 4/thread; B same.
  // chunk c -> row c>>3, global k-chunk kkg = c&7, LDS slot kkg^(row&7).
  const bf16_t* gA[4]; const bf16_t* gB[4];
  int offA[4], offB[4];
#pragma unroll
  for (int q = 0; q < 4; ++q) {
    int c = tid + q * 256;
    int r = c >> 3, kkg = c & 7;
    int ra = row0 + r; if (ra > Mrows - 1) ra = Mrows - 1;  // M-edge clamp
    gA[q] = Amat + (size_t)ra * Kd + kkg * 8;
    offA[q] = r * 64 + (kkg ^ (r & 7)) * 8;
    gB[q] = Bmat + (size_t)(col0 + r) * Kd + kkg * 8;
    offB[q] = 8192 + r * 64 + (kkg ^ (r & 7)) * 8;
  }

  // fragment element-offsets for ks=0 (ks=1: ^32): slot bits 3..5, ks flips bit 5
  const int rl = lane & 15, kc = lane >> 4;
  int aoffs[4], boffs[4];
#pragma unroll
  for (int i = 0; i < 4; ++i) {
    int ra = wm * 64 + i * 16 + rl;
    int rb = wn * 64 + i * 16 + rl;
    aoffs[i] = ra * 64 + ((kc ^ (ra & 7)) * 8);
    boffs[i] = 8192 + rb * 64 + ((kc ^ (rb & 7)) * 8);
  }

  f32x4 acc[4][4] = {};
  f32x4 pA[4], pB[4];
  const int iters = Kd / 64;

  // prologue: tile 0 -> regs -> LDS
#pragma unroll
  for (int q = 0; q < 4; ++q) {
    pA[q] = *(const f32x4*)gA[q]; pB[q] = *(const f32x4*)gB[q];
    gA[q] += 64; gB[q] += 64;
  }
#pragma unroll
  for (int q = 0; q < 4; ++q) {
    *(f32x4*)(lds + offA[q]) = pA[q];
    *(f32x4*)(lds + offB[q]) = pB[q];
  }
  __syncthreads();

  for (int it = 0; it < iters; ++it) {
    const bool more = (it + 1 < iters);
    if (more) {
#pragma unroll
      for (int q = 0; q < 4; ++q) {          // prefetch it+1 into regs
        pA[q] = *(const f32x4*)gA[q]; pB[q] = *(const f32x4*)gB[q];
        gA[q] += 64; gB[q] += 64;
      }
    }
#pragma unroll
    for (int ks = 0; ks < 2; ++ks) {         // compute it from LDS
      bf16x8 af[4], bfr[4];
#pragma unroll
      for (int i = 0; i < 4; ++i) af[i] = *(const bf16x8*)(lds + (aoffs[i] ^ (ks * 32)));
#pragma unroll
      for (int i = 0; i < 4; ++i) bfr[i] = *(const bf16x8*)(lds + (boffs[i] ^ (ks * 32)));
#pragma unroll
      for (int mi = 0; mi < 4; ++mi)
#pragma unroll
        for (int ni = 0; ni < 4; ++ni)
          acc[mi][ni] = __builtin_amdgcn_mfma_f32_16x16x32_bf16(
              af[mi], bfr[ni], acc[mi][ni], 0, 0, 0);
    }
    if (more) {
      __syncthreads();                       // all waves done reading LDS
#pragma unroll
      for (int q = 0; q < 4; ++q) {          // vmcnt wait lands here (covered)
        *(f32x4*)(lds + offA[q]) = pA[q];
        *(f32x4*)(lds + offB[q]) = pB[q];
      }
      __syncthreads();                       // writes visible
    }
  }

  // epilogue. C/D lane layout: col=lane&15, row=(lane>>4)*4+reg [m89-verified]
  const int crow = (lane >> 4) * 4, ccol = lane & 15;
  if constexpr (GELU) {
    __syncthreads();  // all waves done with LDS tiles before sT reuse
#pragma unroll
    for (int p = 0; p < 2; ++p) {
#pragma unroll
      for (int s = 0; s < 2; ++s) {
        int mi = 2 * p + s;
#pragma unroll
        for (int ni = 0; ni < 4; ++ni)
#pragma unroll
          for (int r = 0; r < 4; ++r)
            sT[(wm * 32 + s * 16 + crow + r) * 132 + wn * 64 + ni * 16 + ccol] =
                acc[mi][ni][r];
      }
      __syncthreads();
      const int erow = tid >> 2, eseg = tid & 3;
      const int grow = row0 + (erow >> 5) * 64 + (2 * p + ((erow >> 4) & 1)) * 16 + (erow & 15);
      if (grow < Mrows) {
        const float* src = sT + erow * 132 + eseg * 32;
        const float* bsrc = bias + col0 + eseg * 32;
        bf16_t ov[32];
#pragma unroll
        for (int i = 0; i < 32; ++i)
          ov[i] = (bf16_t)gelu_fast(src[i] + bsrc[i]);
        bf16_t* dst = (bf16_t*)Cmat + (size_t)grow * Ncols + col0 + eseg * 32;
#pragma unroll
        for (int k = 0; k < 4; ++k)
          *(bf16x8*)(dst + k * 8) = *(bf16x8*)(ov + k * 8);
      }
      __syncthreads();
    }
  } else {
#pragma unroll
    for (int ni = 0; ni < 4; ++ni) {
      const int gc = col0 + wn * 64 + ni * 16 + ccol;
      const float bv = bias[gc];
#pragma unroll
      for (int mi = 0; mi < 4; ++mi) {
        const int gr = row0 + wm * 64 + mi * 16 + crow;
#pragma unroll
        for (int r = 0; r < 4; ++r) {
          const int row = gr + r;
          if (row < Mrows)
            Cmat[(size_t)row * Ncols + gc] = acc[mi][ni][r] + bv;
        }
      }
    }
  }
}

extern "C" void kernel_launch(void* const* d_in, const int* in_sizes, int n_in,
                              void* d_out, int out_size, void* d_ws, size_t ws_size,
                              hipStream_t stream) {
  const float* x  = (const float*)d_in[0];
  const float* W1 = (const float*)d_in[1];
  const float* b1 = (const float*)d_in[2];
  const float* A1 = (const float*)d_in[3];
  const float* B1 = (const float*)d_in[4];
  const float* W2 = (const float*)d_in[5];
  const float* b2 = (const float*)d_in[6];
  const float* A2 = (const float*)d_in[7];
  const float* B2 = (const float*)d_in[8];
  float* out = (float*)d_out;

  char* ws = (char*)d_ws;
  bf16_t* xb    = (bf16_t*)ws;                             // 19,365,888 B (pad)
  bf16_t* W1eff = (bf16_t*)(ws + 19366144);                //  4,718,592 B
  bf16_t* W2eff = (bf16_t*)(ws + 19366144 + 4718592);      //  4,718,592 B
  bf16_t* hbuf  = (bf16_t*)(ws + 19366144 + 2 * 4718592);  // 77,463,552 B

  // merged prep: cast (2364) + fold1 (1152) + fold2 (1152)
  prep_kernel<<<4668, 256, 0, stream>>>(x, xb, W1, A1, B1, W1eff,
                                        W2, A2, B2, W2eff);

  // GEMM1: 99 rbands x 24 cols; per XCD 13 rbands rband-fast -> 24*13*8
  gemm_kernel<true, bf16_t, 1, 33792><<<2496, 256, 0, stream>>>(
      xb, W1eff, b1, hbuf, M_ROWS, H_DIM, D_DIM);
  // GEMM2: 99 rbands x 6 cols; two 4-XCD groups x 3 cols col-fast -> 25*3*8
  gemm_kernel<false, float, 2, 32768><<<600, 256, 0, stream>>>(
      hbuf, W2eff, b2, out, M_ROWS, D_DIM, H_DIM);
}